// Round 4
// baseline (300.608 us; speedup 1.0000x reference)
//
#include <hip/hip_runtime.h>

#define EPSF 1e-8f
#define CCH 128
#define HWSZ 65536
#define NPIX 262144
#define KTOP 13107
#define LN2F 0.6931471805599453f

// ws layout (32-bit words)
#define WS_SUM    0      // [512] f32: sumP[128], sumsqP[128], sumT[128], sumsqT[128]
#define WS_CST    512    // [512] f32: float4 per channel c: (m_p, i_p, m_t, i_t)
#define WS_WGT    1024   // [9] f32 softmax weights
#define WS_MINKEY 1040
#define WS_MAXKEY 1041
#define WS_BSTAR  1042
#define WS_CNTAB  1043
#define WS_LO2    1044
#define WS_W2     1045
#define WS_K2     1046
#define WS_SUMAB  1048
#define WS_H1     1056   // [4096] u32
#define WS_H2C    5152   // [4096] u32
#define WS_H2S    9248   // [4096] f32
#define WS_TOTAL  13344

__device__ __forceinline__ unsigned fkey(float f){
  unsigned u = __float_as_uint(f);
  return (u & 0x80000000u) ? ~u : (u | 0x80000000u);
}
__device__ __forceinline__ float funkey(unsigned k){
  unsigned u = (k & 0x80000000u) ? (k & 0x7fffffffu) : ~k;
  return __uint_as_float(u);
}

// ---- float4 helpers (componentwise) ----
__device__ __forceinline__ float4 mk4(float s){ return make_float4(s,s,s,s); }
__device__ __forceinline__ float4 add4(float4 a,float4 b){ return make_float4(a.x+b.x,a.y+b.y,a.z+b.z,a.w+b.w); }
__device__ __forceinline__ float4 sub4(float4 a,float4 b){ return make_float4(a.x-b.x,a.y-b.y,a.z-b.z,a.w-b.w); }
__device__ __forceinline__ float4 mul4(float4 a,float4 b){ return make_float4(a.x*b.x,a.y*b.y,a.z*b.z,a.w*b.w); }
__device__ __forceinline__ float4 fma4(float4 a,float4 b,float4 c){ return make_float4(fmaf(a.x,b.x,c.x),fmaf(a.y,b.y,c.y),fmaf(a.z,b.z,c.z),fmaf(a.w,b.w,c.w)); }
__device__ __forceinline__ float4 msub4(float4 a,float4 b,float4 c){ return make_float4(fmaf(a.x,b.x,-c.x),fmaf(a.y,b.y,-c.y),fmaf(a.z,b.z,-c.z),fmaf(a.w,b.w,-c.w)); }
__device__ __forceinline__ float4 fma4s(float4 a,float s,float o){ return make_float4(fmaf(a.x,s,o),fmaf(a.y,s,o),fmaf(a.z,s,o),fmaf(a.w,s,o)); }
__device__ __forceinline__ float4 min4(float4 a,float4 b){ return make_float4(fminf(a.x,b.x),fminf(a.y,b.y),fminf(a.z,b.z),fminf(a.w,b.w)); }
__device__ __forceinline__ float4 max4(float4 a,float4 b){ return make_float4(fmaxf(a.x,b.x),fmaxf(a.y,b.y),fmaxf(a.z,b.z),fmaxf(a.w,b.w)); }
__device__ __forceinline__ float4 rcp4(float4 a){ return make_float4(1.f/a.x,1.f/a.y,1.f/a.z,1.f/a.w); }
__device__ __forceinline__ float4 sqrt4(float4 a){ return make_float4(sqrtf(a.x),sqrtf(a.y),sqrtf(a.z),sqrtf(a.w)); }
__device__ __forceinline__ float4 log24(float4 a){ return make_float4(__log2f(a.x),__log2f(a.y),__log2f(a.z),__log2f(a.w)); }
__device__ __forceinline__ float4 shflx4(float4 v,int m){ return make_float4(__shfl_xor(v.x,m),__shfl_xor(v.y,m),__shfl_xor(v.z,m),__shfl_xor(v.w,m)); }
__device__ __forceinline__ float4 shflb4(float4 v,int s){ return make_float4(__shfl(v.x,s),__shfl(v.y,s),__shfl(v.z,s),__shfl(v.w,s)); }
__device__ __forceinline__ float4 vs4(float4 v,float s){ return make_float4(v.x*s,v.y*s,v.z*s,v.w*s); }

__global__ __launch_bounds__(256) void initWs(unsigned* __restrict__ wsu){
  int idx = blockIdx.x*256 + threadIdx.x;
  if (idx < WS_TOTAL) wsu[idx] = (idx == WS_MINKEY) ? 0xFFFFFFFFu : 0u;
}

// per-channel sums over (B,H,W) for both tensors
__global__ __launch_bounds__(512) void bnSumKernel(const float* __restrict__ rec,
                                                   const float* __restrict__ tgt,
                                                   float* __restrict__ wsf){
  int blk = blockIdx.x;            // 0..1023: tensor(2) x b(4) x c(128)
  int tensor = blk >> 9;
  int rem = blk & 511;
  int c = rem & 127;
  int b = rem >> 7;
  const float* src = (tensor==0 ? rec : tgt) + ((size_t)(b*CCH + c))*HWSZ;
  const float4* src4 = (const float4*)src;
  float s=0.f, q=0.f;
  #pragma unroll 4
  for (int j=threadIdx.x; j<HWSZ/4; j+=512){
    float4 v = src4[j];
    s += v.x+v.y+v.z+v.w;
    q += v.x*v.x + v.y*v.y + v.z*v.z + v.w*v.w;
  }
  for (int off=1; off<64; off<<=1){ s += __shfl_xor(s,off); q += __shfl_xor(q,off); }
  __shared__ float ls[8], lq[8];
  int wid = threadIdx.x >> 6;
  if ((threadIdx.x & 63)==0){ ls[wid]=s; lq[wid]=q; }
  __syncthreads();
  if (threadIdx.x==0){
    float S=0,Q=0;
    for (int i=0;i<8;i++){ S+=ls[i]; Q+=lq[i]; }
    atomicAdd(&wsf[tensor*256 + c], S);
    atomicAdd(&wsf[tensor*256 + 128 + c], Q);
  }
}

// bn mean/inv-std per channel (both tensors) + softmax weights
__global__ __launch_bounds__(256) void finalizeKernel(const float* __restrict__ lw,
                                                      float* __restrict__ wsf){
  int tid = threadIdx.x;
  {
    int tensor = tid >> 7;
    int c = tid & 127;
    float S = wsf[tensor*256 + c];
    float Q = wsf[tensor*256 + 128 + c];
    const float N = 262144.f;
    float mean = S / N;
    float var = fmaxf((Q - S*S/N) / (N - 1.f), 0.f);
    float inv = 1.f/(sqrtf(var)+EPSF);
    wsf[WS_CST + c*4 + tensor*2 + 0] = mean;
    wsf[WS_CST + c*4 + tensor*2 + 1] = inv;
  }
  if (tid==0){
    float m = -1e30f;
    for (int i=0;i<9;i++) m = fmaxf(m, lw[i]);
    float e[9], sum=0.f;
    for (int i=0;i<9;i++){ e[i]=expf(lw[i]-m); sum+=e[i]; }
    for (int i=0;i<9;i++) wsf[WS_WGT+i] = e[i]/sum;
  }
}

// main kernel: block = 64 pixels, 4 waves; wave w -> channels [32w,32w+32);
// lane l: cl=l>>4 (channel sub-group), g=l&15 (pixel quad). Each lane loads
// float4 (4 pixels) for 8 channels x 2 tensors = 16 fat loads (1KB/wave-instr).
// asm fences pin loaded data in VGPRs (defeat rematerialization).
__global__ __launch_bounds__(256, 2) void mainKernel(const float* __restrict__ rec,
                                                     const float* __restrict__ tgt,
                                                     const float* __restrict__ wsf,
                                                     unsigned* __restrict__ wsu,
                                                     float* __restrict__ errMap){
  __shared__ float4 cst[128];
  __shared__ float wgt[16];
  __shared__ float4 red[16][4][16];
  __shared__ float4 sidred[2][4][16];
  int tid = threadIdx.x;
  if (tid < 128) cst[tid] = ((const float4*)(wsf + WS_CST))[tid];
  if (tid < 9)  wgt[tid] = wsf[WS_WGT + tid];
  __syncthreads();

  int w = tid>>6, l = tid&63, cl = l>>4, g = l&15;
  int P0 = blockIdx.x*64 + g*4;
  int b = P0 >> 16;
  int hw = P0 & (HWSZ-1);
  const float* pBase = rec + (size_t)b*CCH*HWSZ + hw;
  const float* tBase = tgt + (size_t)b*CCH*HWSZ + hw;

  float4 p4[8], t4[8];
  #pragma unroll
  for (int j=0;j<8;j++){
    int c = w*32 + cl + j*4;
    p4[j] = *(const float4*)(pBase + (size_t)c*HWSZ);
    t4[j] = *(const float4*)(tBase + (size_t)c*HWSZ);
  }
  #pragma unroll
  for (int j=0;j<8;j++){
    asm volatile("" : "+v"(p4[j].x), "+v"(p4[j].y), "+v"(p4[j].z), "+v"(p4[j].w));
    asm volatile("" : "+v"(t4[j].x), "+v"(t4[j].y), "+v"(t4[j].z), "+v"(t4[j].w));
  }

  const float4 big = mk4(3.4e38f), nbig = mk4(-3.4e38f), zero = mk4(0.f);
  float4 psum=zero,psumsq=zero,tsum=zero,tsumsq=zero,ptsum=zero;
  float4 pmin=big,pmax=nbig,tmin=big,tmax=nbig;
  float4 bS1=zero,bS11=zero,bS2=zero,bS22=zero,bS12=zero,bMp=big,bMt=big;

  #pragma unroll
  for (int j=0;j<8;j++){
    float4 pv=p4[j], tv=t4[j];
    psum=add4(psum,pv); psumsq=fma4(pv,pv,psumsq);
    tsum=add4(tsum,tv); tsumsq=fma4(tv,tv,tsumsq);
    ptsum=fma4(pv,tv,ptsum);
    pmin=min4(pmin,pv); pmax=max4(pmax,pv);
    tmin=min4(tmin,tv); tmax=max4(tmax,tv);
    float4 c4 = cst[w*32 + cl + j*4];
    float mip = c4.x*c4.y, mit = c4.z*c4.w;
    float4 bp = fma4s(pv, c4.y, -mip);
    float4 bt = fma4s(tv, c4.w, -mit);
    bS1=add4(bS1,bp); bS11=fma4(bp,bp,bS11);
    bS2=add4(bS2,bt); bS22=fma4(bt,bt,bS22);
    bS12=fma4(bp,bt,bS12);
    bMp=min4(bMp,bp); bMt=min4(bMt,bt);
  }

  // reduce over cl (lanes g, g+16, g+32, g+48)
  #define RS(v) v=add4(v,shflx4(v,16)); v=add4(v,shflx4(v,32));
  #define RN(v) v=min4(v,shflx4(v,16)); v=min4(v,shflx4(v,32));
  #define RX(v) v=max4(v,shflx4(v,16)); v=max4(v,shflx4(v,32));
  RS(psum) RS(psumsq) RS(tsum) RS(tsumsq) RS(ptsum)
  RN(pmin) RX(pmax) RN(tmin) RX(tmax)
  RS(bS1) RS(bS11) RS(bS2) RS(bS22) RS(bS12)
  RN(bMp) RN(bMt)
  #undef RS
  #undef RN
  #undef RX

  if (cl==0){
    red[0][w][g]=psum;  red[1][w][g]=psumsq; red[2][w][g]=tsum;  red[3][w][g]=tsumsq;
    red[4][w][g]=ptsum; red[5][w][g]=pmin;   red[6][w][g]=pmax;  red[7][w][g]=tmin;
    red[8][w][g]=tmax;  red[9][w][g]=bS1;    red[10][w][g]=bS11; red[11][w][g]=bS2;
    red[12][w][g]=bS22; red[13][w][g]=bS12;  red[14][w][g]=bMp;  red[15][w][g]=bMt;
  }
  __syncthreads();

  #define RD4(s) add4(add4(red[s][0][g],red[s][1][g]),add4(red[s][2][g],red[s][3][g]))
  #define RDN(s) min4(min4(red[s][0][g],red[s][1][g]),min4(red[s][2][g],red[s][3][g]))
  #define RDX(s) max4(max4(red[s][0][g],red[s][1][g]),max4(red[s][2][g],red[s][3][g]))

  // per-pixel SID constants on cl==0 lanes, then wave-broadcast
  float4 fp=zero,Bp=zero,ft=zero,Bt=zero,fbp=zero,Bbp=zero,fbt=zero,Bbt=zero;
  if (cl==0){
    float4 S=RD4(0), T=RD4(2);
    float4 pn=RDN(5), px=RDX(6), tn=RDN(7), tx=RDX(8);
    float4 B1=RD4(9), B2=RD4(11), Mp=RDN(14), Mt=RDN(15);
    float4 smp = rcp4(add4(sub4(px,pn), mk4(EPSF)));
    float4 smt = rcp4(add4(sub4(tx,tn), mk4(EPSF)));
    float4 dp = add4(mul4(sub4(S, vs4(pn,128.f)), smp), mk4(EPSF));
    float4 dt = add4(mul4(sub4(T, vs4(tn,128.f)), smt), mk4(EPSF));
    fp = mul4(smp, rcp4(dp)); Bp = mul4(pn, fp);
    ft = mul4(smt, rcp4(dt)); Bt = mul4(tn, ft);
    fbp = rcp4(add4(sub4(B1, vs4(Mp,128.f)), mk4(EPSF))); Bbp = mul4(Mp, fbp);
    fbt = rcp4(add4(sub4(B2, vs4(Mt,128.f)), mk4(EPSF))); Bbt = mul4(Mt, fbt);
  }
  fp=shflb4(fp,g);  Bp=shflb4(Bp,g);  ft=shflb4(ft,g);  Bt=shflb4(Bt,g);
  fbp=shflb4(fbp,g); Bbp=shflb4(Bbp,g); fbt=shflb4(fbt,g); Bbt=shflb4(Bbt,g);

  // SID pass from register-resident data
  float4 sid_mm=zero, sid_bn=zero;
  #pragma unroll
  for (int j=0;j<8;j++){
    float4 pv=p4[j], tv=t4[j];
    float4 pp = max4(msub4(pv,fp,Bp), mk4(EPSF));
    float4 tp = max4(msub4(tv,ft,Bt), mk4(EPSF));
    sid_mm = fma4(sub4(pp,tp), sub4(log24(pp),log24(tp)), sid_mm);
    float4 c4 = cst[w*32 + cl + j*4];
    float mip = c4.x*c4.y, mit = c4.z*c4.w;
    float4 bp = fma4s(pv, c4.y, -mip);
    float4 bt = fma4s(tv, c4.w, -mit);
    float4 qp = max4(msub4(bp,fbp,Bbp), mk4(EPSF));
    float4 qt = max4(msub4(bt,fbt,Bbt), mk4(EPSF));
    sid_bn = fma4(sub4(qp,qt), sub4(log24(qp),log24(qt)), sid_bn);
  }
  sid_mm=add4(sid_mm,shflx4(sid_mm,16)); sid_mm=add4(sid_mm,shflx4(sid_mm,32));
  sid_bn=add4(sid_bn,shflx4(sid_bn,16)); sid_bn=add4(sid_bn,shflx4(sid_bn,32));
  if (cl==0){ sidred[0][w][g]=sid_mm; sidred[1][w][g]=sid_bn; }
  __syncthreads();

  if (w==0 && cl==0){
    const float Ci = 1.0f/128.0f;
    float4 S=RD4(0), SS=RD4(1), T=RD4(2), TT=RD4(3), PT=RD4(4);
    float4 pn=RDN(5), px=RDX(6), tn=RDN(7), tx=RDX(8);
    float4 B1=RD4(9), B11=RD4(10), B2=RD4(11), B22=RD4(12), B12=RD4(13);
    float4 smp = rcp4(add4(sub4(px,pn), mk4(EPSF)));
    float4 smt = rcp4(add4(sub4(tx,tn), mk4(EPSF)));
    float4 meanp = vs4(S,Ci), meant = vs4(T,Ci);
    float4 varp = max4(vs4(sub4(SS, vs4(mul4(S,S),Ci)), 1.f/127.f), zero);
    float4 vart = max4(vs4(sub4(TT, vs4(mul4(T,T),Ci)), 1.f/127.f), zero);
    float4 zip = rcp4(add4(sqrt4(varp), mk4(EPSF)));
    float4 zit = rcp4(add4(sqrt4(vart), mk4(EPSF)));

    auto metrics4 = [&](float4 S1,float4 S11,float4 S2,float4 S22,float4 S12,
                        float4& sam,float4& pear){
      float4 npn = max4(sqrt4(max4(S11,zero)), mk4(EPSF));
      float4 ntn = max4(sqrt4(max4(S22,zero)), mk4(EPSF));
      sam = sub4(mk4(1.f), mul4(S12, rcp4(mul4(npn,ntn))));
      float4 cov = sub4(S12, vs4(mul4(S1,S2),Ci));
      float4 vp = max4(sub4(S11, vs4(mul4(S1,S1),Ci)), zero);
      float4 vt = max4(sub4(S22, vs4(mul4(S2,S2),Ci)), zero);
      pear = sub4(mk4(1.f), mul4(cov, rcp4(mul4(sqrt4(add4(vp,mk4(EPSF))),
                                               sqrt4(add4(vt,mk4(EPSF)))))));
    };
    auto affine4 = [&](float4 ap,float4 sp,float4 at,float4 st,
                       float4& sam,float4& pear){
      float4 S1 = mul4(sub4(S, vs4(ap,128.f)), sp);
      float4 S11 = mul4(add4(sub4(SS, vs4(mul4(ap,S),2.f)), vs4(mul4(ap,ap),128.f)),
                        mul4(sp,sp));
      float4 S2 = mul4(sub4(T, vs4(at,128.f)), st);
      float4 S22 = mul4(add4(sub4(TT, vs4(mul4(at,T),2.f)), vs4(mul4(at,at),128.f)),
                        mul4(st,st));
      float4 S12 = mul4(add4(sub4(sub4(PT, mul4(at,S)), mul4(ap,T)),
                             vs4(mul4(ap,at),128.f)),
                        mul4(sp,st));
      metrics4(S1,S11,S2,S22,S12,sam,pear);
    };

    float4 sam_mm,pear_mm,sam_z,pear_z,sam_bn,pear_bn;
    affine4(pn,smp,tn,smt,sam_mm,pear_mm);
    affine4(meanp,zip,meant,zit,sam_z,pear_z);
    metrics4(B1,B11,B2,B22,B12,sam_bn,pear_bn);

    float4 smm = vs4(add4(add4(sidred[0][0][g],sidred[0][1][g]),
                          add4(sidred[0][2][g],sidred[0][3][g])), LN2F);
    float4 sbn = vs4(add4(add4(sidred[1][0][g],sidred[1][1][g]),
                          add4(sidred[1][2][g],sidred[1][3][g])), LN2F);

    float4 err = vs4(sam_mm,wgt[0]);
    err = add4(err, vs4(pear_mm,wgt[1]));
    err = add4(err, vs4(smm, wgt[2]+wgt[5]));
    err = add4(err, vs4(sam_z,wgt[3]));
    err = add4(err, vs4(pear_z,wgt[4]));
    err = add4(err, vs4(sam_bn,wgt[6]));
    err = add4(err, vs4(pear_bn,wgt[7]));
    err = add4(err, vs4(sbn,wgt[8]));

    errMap[P0+0]=err.x; errMap[P0+1]=err.y; errMap[P0+2]=err.z; errMap[P0+3]=err.w;

    float mn = fminf(fminf(err.x,err.y),fminf(err.z,err.w));
    float mx = fmaxf(fmaxf(err.x,err.y),fmaxf(err.z,err.w));
    #pragma unroll
    for (int off=1; off<16; off<<=1){
      mn = fminf(mn, __shfl_xor(mn,off));
      mx = fmaxf(mx, __shfl_xor(mx,off));
    }
    if (l==0){
      atomicMin(&wsu[WS_MINKEY], fkey(mn));
      atomicMax(&wsu[WS_MAXKEY], fkey(mx));
    }
  }
  #undef RD4
  #undef RDN
  #undef RDX
}

__global__ __launch_bounds__(256) void hist1Kernel(const float* __restrict__ err,
                                                   unsigned* __restrict__ wsu){
  __shared__ unsigned h[4096];
  int tid = threadIdx.x;
  for (int i=tid;i<4096;i+=256) h[i]=0u;
  __syncthreads();
  float lo = funkey(wsu[WS_MINKEY]);
  float hi = funkey(wsu[WS_MAXKEY]);
  float invw = 4096.f / fmaxf(hi-lo, 1e-30f);
  int base = blockIdx.x*2048 + tid;
  for (int j=0;j<8;j++){
    float v = err[base + j*256];
    int idx = (int)fminf(fmaxf((v-lo)*invw, 0.f), 4095.f);
    atomicAdd(&h[idx], 1u);
  }
  __syncthreads();
  for (int i=tid;i<4096;i+=256){ unsigned c=h[i]; if (c) atomicAdd(&wsu[WS_H1+i], c); }
}

__global__ __launch_bounds__(256) void scan1Kernel(float* __restrict__ wsf,
                                                   unsigned* __restrict__ wsu){
  __shared__ unsigned counts[4096];
  __shared__ unsigned s[256];
  int tid = threadIdx.x;
  for (int i=tid;i<4096;i+=256) counts[i]=wsu[WS_H1+i];
  __syncthreads();
  unsigned part=0;
  for (int j=0;j<16;j++) part += counts[tid*16+j];
  s[tid]=part; __syncthreads();
  for (int off=1; off<256; off<<=1){
    unsigned v = (tid+off<256)? s[tid+off] : 0u;
    __syncthreads();
    s[tid] += v;
    __syncthreads();
  }
  float lo = funkey(wsu[WS_MINKEY]);
  float hi = funkey(wsu[WS_MAXKEY]);
  float w1 = fmaxf(hi-lo, 1e-30f) * (1.f/4096.f);
  unsigned cum = (tid<255)? s[tid+1] : 0u;
  for (int j=15;j>=0;j--){
    int bin = tid*16+j;
    unsigned cn = cum + counts[bin];
    if (cum < (unsigned)KTOP && cn >= (unsigned)KTOP){
      wsu[WS_BSTAR] = (unsigned)bin;
      wsu[WS_CNTAB] = cum;
      wsu[WS_K2]    = (unsigned)KTOP - cum;
      wsf[WS_LO2]   = lo + (float)bin*w1;
      wsf[WS_W2]    = w1*(1.f/4096.f);
    }
    cum = cn;
  }
}

__global__ __launch_bounds__(256) void hist2Kernel(const float* __restrict__ err,
                                                   float* __restrict__ wsf,
                                                   unsigned* __restrict__ wsu){
  __shared__ unsigned h2[4096];
  __shared__ float s2[4096];
  __shared__ float ls[4];
  int tid = threadIdx.x;
  for (int i=tid;i<4096;i+=256){ h2[i]=0u; s2[i]=0.f; }
  __syncthreads();
  float lo = funkey(wsu[WS_MINKEY]);
  float hi = funkey(wsu[WS_MAXKEY]);
  float invw = 4096.f / fmaxf(hi-lo, 1e-30f);
  int bstar = (int)wsu[WS_BSTAR];
  float lo2 = wsf[WS_LO2];
  float w2  = wsf[WS_W2];
  float invw2 = 1.f / w2;
  float mySum = 0.f;
  int base = blockIdx.x*2048 + tid;
  for (int j=0;j<8;j++){
    float v = err[base + j*256];
    int idx = (int)fminf(fmaxf((v-lo)*invw, 0.f), 4095.f);
    if (idx > bstar){
      mySum += v;
    } else if (idx == bstar){
      int i2 = (int)fminf(fmaxf((v-lo2)*invw2, 0.f), 4095.f);
      atomicAdd(&h2[i2], 1u);
      atomicAdd(&s2[i2], v);
    }
  }
  for (int off=1; off<64; off<<=1) mySum += __shfl_xor(mySum, off);
  if ((tid&63)==0) ls[tid>>6] = mySum;
  __syncthreads();
  if (tid==0) atomicAdd(&wsf[WS_SUMAB], ls[0]+ls[1]+ls[2]+ls[3]);
  for (int i=tid;i<4096;i+=256){
    unsigned c = h2[i]; if (c) atomicAdd(&wsu[WS_H2C+i], c);
    float sv = s2[i];   if (sv != 0.f) atomicAdd(&wsf[WS_H2S+i], sv);
  }
}

__global__ __launch_bounds__(256) void scan2Kernel(float* __restrict__ wsf,
                                                   unsigned* __restrict__ wsu,
                                                   float* __restrict__ out){
  __shared__ unsigned cnt[4096];
  __shared__ float sm[4096];
  __shared__ unsigned sC[256];
  __shared__ float sS[256];
  int tid = threadIdx.x;
  for (int i=tid;i<4096;i+=256){ cnt[i]=wsu[WS_H2C+i]; sm[i]=wsf[WS_H2S+i]; }
  __syncthreads();
  unsigned pc=0; float ps=0.f;
  for (int j=0;j<16;j++){ pc+=cnt[tid*16+j]; ps+=sm[tid*16+j]; }
  sC[tid]=pc; sS[tid]=ps; __syncthreads();
  for (int off=1; off<256; off<<=1){
    unsigned vc = (tid+off<256)? sC[tid+off] : 0u;
    float vs    = (tid+off<256)? sS[tid+off] : 0.f;
    __syncthreads();
    sC[tid] += vc; sS[tid] += vs;
    __syncthreads();
  }
  unsigned k2 = wsu[WS_K2];
  float lo2 = wsf[WS_LO2], w2 = wsf[WS_W2];
  unsigned cum = (tid<255)? sC[tid+1] : 0u;
  float cums   = (tid<255)? sS[tid+1] : 0.f;
  for (int j=15;j>=0;j--){
    int bin = tid*16+j;
    unsigned cn = cum + cnt[bin];
    float sn = cums + sm[bin];
    if (cum < k2 && cn >= k2){
      float val = lo2 + ((float)bin + 0.5f)*w2;
      float total = wsf[WS_SUMAB] + cums + (float)(k2 - cum)*val;
      out[0] = total / (float)KTOP;
    }
    cum = cn; cums = sn;
  }
}

extern "C" void kernel_launch(void* const* d_in, const int* in_sizes, int n_in,
                              void* d_out, int out_size, void* d_ws, size_t ws_size,
                              hipStream_t stream){
  const float* rec = (const float*)d_in[0];
  const float* tgt = (const float*)d_in[1];
  const float* lw  = (const float*)d_in[2];
  float* out = (float*)d_out;
  float* wsf = (float*)d_ws;
  unsigned* wsu = (unsigned*)d_ws;

  hipLaunchKernelGGL(initWs, dim3((WS_TOTAL+255)/256), dim3(256), 0, stream, wsu);
  hipLaunchKernelGGL(bnSumKernel, dim3(1024), dim3(512), 0, stream, rec, tgt, wsf);
  hipLaunchKernelGGL(finalizeKernel, dim3(1), dim3(256), 0, stream, lw, wsf);
  hipLaunchKernelGGL(mainKernel, dim3(NPIX/64), dim3(256), 0, stream, rec, tgt, wsf, wsu, out+1);
  hipLaunchKernelGGL(hist1Kernel, dim3(128), dim3(256), 0, stream, out+1, wsu);
  hipLaunchKernelGGL(scan1Kernel, dim3(1), dim3(256), 0, stream, wsf, wsu);
  hipLaunchKernelGGL(hist2Kernel, dim3(128), dim3(256), 0, stream, out+1, wsf, wsu);
  hipLaunchKernelGGL(scan2Kernel, dim3(1), dim3(256), 0, stream, wsf, wsu, out);
}